// Round 12
// baseline (381.625 us; speedup 1.0000x reference)
//
#include <hip/hip_runtime.h>

#define NN 50000
#define FF 300
#define DD 128
#define HH 4
#define CC 32
#define EE 640000
#define RR 200
#define LL 2
#define SB ((NN + 255) / 256)     // scan blocks = 196
#define PK 320                    // proj K padded to multiple of 64
#define WTOT (128 * PK + 4 * 128 * 128)
#define HB ((EE + 255) / 256)     // hist blocks in prep
#define WB ((WTOT + 255) / 256)   // wconv blocks in prep
#define RB (LL * RR / 2)          // relproj blocks in prep (2 lr per block)

typedef unsigned short u16;
typedef unsigned int u32;
typedef __attribute__((ext_vector_type(8))) short short8;   // 8 bf16 (4 VGPRs)
typedef __attribute__((ext_vector_type(4))) float floatx4;  // MFMA accumulator

__device__ __forceinline__ float bf2f(u16 u) {
    union { u32 i; float f; } v; v.i = ((u32)u) << 16; return v.f;
}
__device__ __forceinline__ u16 f2bf(float f) {
    u32 u = __float_as_uint(f);
    u32 r = (u >> 16) & 1u;
    u += 0x7fffu + r;
    return (u16)(u >> 16);
}
// unpack 2 bf16 from one u32 (lo = lower address = even channel)
__device__ __forceinline__ void bf2x(u32 p, float& lo, float& hi) {
    lo = __uint_as_float(p << 16);
    hi = __uint_as_float(p & 0xffff0000u);
}

// block-wide (256 threads) scan: returns exclusive prefix of v; *total = block sum
__device__ __forceinline__ int block_excl_scan(int v, int* lds4, int* total) {
    int lane = threadIdx.x & 63, wid = threadIdx.x >> 6;
    int x = v;
    #pragma unroll
    for (int off = 1; off < 64; off <<= 1) {
        int y = __shfl_up(x, off, 64);
        if (lane >= off) x += y;
    }
    if (lane == 63) lds4[wid] = x;
    __syncthreads();
    int add = 0;
    #pragma unroll
    for (int w = 0; w < 4; w++) add += (w < wid) ? lds4[w] : 0;
    *total = lds4[0] + lds4[1] + lds4[2] + lds4[3];
    return x + add - v;
}

// ---------------- fused prep: hist | weight transpose-convert | relproj (fp32 out)
__global__ __launch_bounds__(256)
void prep_kernel(const int* __restrict__ ei, int* __restrict__ counts,
                 const float* __restrict__ proj_w, const float* __restrict__ w_l,
                 const float* __restrict__ w_r, u16* __restrict__ wt,
                 const float* __restrict__ rel_emb, const float* __restrict__ w_e,
                 float* __restrict__ erel)
{
    __shared__ float rv[2][DD];
    int b = blockIdx.x, tid = threadIdx.x;
    if (b < HB) {
        // degree histogram
        int e = b * 256 + tid;
        if (e < EE) atomicAdd(&counts[ei[EE + e]], 1);
    } else if (b < HB + WB) {
        // fp32 [K][128] -> bf16 WT [128][K]: [proj 128xPK pad0] [wl0][wl1][wr0][wr1]
        int i = (b - HB) * 256 + tid;
        if (i < WTOT) {
            float v;
            if (i < 128 * PK) {
                int n = i / PK, k = i - n * PK;
                v = (k < FF) ? proj_w[(size_t)k * DD + n] : 0.f;
            } else {
                int j = i - 128 * PK;
                int seg = j >> 14;          // wl0, wl1, wr0, wr1
                int r = j & 16383;
                int n = r >> 7, k = r & 127;
                const float* src = (seg < 2) ? (w_l + (size_t)seg * DD * DD)
                                             : (w_r + (size_t)(seg - 2) * DD * DD);
                v = src[(size_t)k * DD + n];
            }
            wt[i] = f2bf(v);
        }
    } else {
        // erel[l*RR+r][d] = rel_emb[r,:] @ w_e[l][:,d]   (2 lr per block, fp32 out)
        int half = tid >> 7, d = tid & 127;
        int lr = (b - HB - WB) * 2 + half;
        int l = lr / RR, r = lr - l * RR;
        rv[half][d] = rel_emb[r * DD + d];
        __syncthreads();
        const float* W = w_e + (size_t)l * DD * DD;
        float acc = 0.f;
        #pragma unroll 8
        for (int k = 0; k < DD; k++) acc += rv[half][k] * W[k * DD + d];
        erel[(size_t)lr * DD + d] = acc;
    }
}

// ---------------- MFMA bf16 GEMM, BK=64: C = A @ WT^T + bias
// OUT1F32: blockIdx.y==0 output is fp32 (xl for the node gather), else bf16.
template<bool ABF16, bool GATHER, bool OUT1F32>
__global__ __launch_bounds__(256)
void gemm_mfma_kernel(const void* __restrict__ A_, const int* __restrict__ rowidx,
                      int lda, int K, int Ka, int ldb,
                      const u16* __restrict__ BT1, const float* __restrict__ bias1,
                      void* __restrict__ C1,
                      const u16* __restrict__ BT2, const float* __restrict__ bias2,
                      u16* __restrict__ C2, int M)
{
    const u16*   BT   = (blockIdx.y == 0) ? BT1 : BT2;
    const float* bias = (blockIdx.y == 0) ? bias1 : bias2;

    // pad 8 u16 -> 144 B rows: bank stride 4, 2-way conflicts only (free, m136)
    __shared__ u16 As[128][72];
    __shared__ u16 Bs[128][72];   // Bs[n][k]
    int tid  = threadIdx.x;
    int m0   = blockIdx.x * 128;
    int wave = tid >> 6, lane = tid & 63;
    int quad = lane >> 4, l16 = lane & 15;
    int wrow = (wave >> 1) * 64, wcol = (wave & 1) * 64;

    floatx4 acc[4][4];
    #pragma unroll
    for (int i = 0; i < 4; i++)
        #pragma unroll
        for (int j = 0; j < 4; j++) acc[i][j] = (floatx4){0.f, 0.f, 0.f, 0.f};

    int ar = tid >> 1, ah = tid & 1;   // row, k-half (32 each)
    int arow = m0 + ar;
    int rid = (arow < M) ? (GATHER ? rowidx[arow] : arow) : 0;

    for (int kk = 0; kk < K; kk += 64) {
        #pragma unroll
        for (int q = 0; q < 2; q++) {
            int kb = kk + ah * 32 + q * 16;
            u16 tmp[16];
            if (ABF16) {
                const u16* Ap = (const u16*)A_ + (size_t)rid * lda + kb;
                if (kb + 16 <= Ka) {
                    *(short8*)&tmp[0] = *(const short8*)Ap;
                    *(short8*)&tmp[8] = *(const short8*)(Ap + 8);
                } else {
                    #pragma unroll
                    for (int j = 0; j < 16; j++) tmp[j] = (kb + j < Ka) ? Ap[j] : (u16)0;
                }
            } else {
                const float* Ap = (const float*)A_ + (size_t)rid * lda + kb;
                if (kb + 16 <= Ka) {
                    #pragma unroll
                    for (int qq = 0; qq < 4; qq++) {
                        float4 f = *(const float4*)(Ap + qq * 4);
                        tmp[qq*4+0] = f2bf(f.x); tmp[qq*4+1] = f2bf(f.y);
                        tmp[qq*4+2] = f2bf(f.z); tmp[qq*4+3] = f2bf(f.w);
                    }
                } else {
                    #pragma unroll
                    for (int j = 0; j < 16; j++) tmp[j] = (kb + j < Ka) ? f2bf(Ap[j]) : (u16)0;
                }
            }
            *(short8*)&As[ar][ah * 32 + q * 16]     = *(short8*)&tmp[0];
            *(short8*)&As[ar][ah * 32 + q * 16 + 8] = *(short8*)&tmp[8];
        }
        {
            const u16* Bp = BT + (size_t)ar * ldb + kk + ah * 32;
            #pragma unroll
            for (int q = 0; q < 4; q++)
                *(short8*)&Bs[ar][ah * 32 + q * 8] = *(const short8*)(Bp + q * 8);
        }
        __syncthreads();
        #pragma unroll
        for (int ks = 0; ks < 2; ks++) {
            short8 af[4], bfr[4];
            #pragma unroll
            for (int i = 0; i < 4; i++)
                af[i] = *(const short8*)&As[wrow + i * 16 + l16][ks * 32 + quad * 8];
            #pragma unroll
            for (int j = 0; j < 4; j++)
                bfr[j] = *(const short8*)&Bs[wcol + j * 16 + l16][ks * 32 + quad * 8];
            #pragma unroll
            for (int i = 0; i < 4; i++)
                #pragma unroll
                for (int j = 0; j < 4; j++)
                    acc[i][j] = __builtin_amdgcn_mfma_f32_16x16x32_bf16(
                        af[i], bfr[j], acc[i][j], 0, 0, 0);
        }
        __syncthreads();
    }

    // epilogue: C/D layout col=lane&15, row=quad*4+reg (m89)
    #pragma unroll
    for (int i = 0; i < 4; i++) {
        #pragma unroll
        for (int rr = 0; rr < 4; rr++) {
            int row = m0 + wrow + i * 16 + quad * 4 + rr;
            if (row < M) {
                #pragma unroll
                for (int j = 0; j < 4; j++) {
                    int col = wcol + j * 16 + l16;
                    float v = acc[i][j][rr] + bias[col];
                    if (OUT1F32 && blockIdx.y == 0) {
                        ((float*)C1)[(size_t)row * DD + col] = v;
                    } else {
                        u16* Cb = (blockIdx.y == 0) ? (u16*)C1 : C2;
                        Cb[(size_t)row * DD + col] = f2bf(v);
                    }
                }
            }
        }
    }
}

// ---------------- CSR scan (hierarchical, no final add pass) + scatter (packed)
__global__ __launch_bounds__(256)
void scan_local_kernel(const int* __restrict__ counts, int* __restrict__ offsets,
                       int* __restrict__ bsum)
{
    __shared__ int lds4[4];
    int i = blockIdx.x * 256 + threadIdx.x;
    int v = (i < NN) ? counts[i] : 0;
    int total;
    int ex = block_excl_scan(v, lds4, &total);
    if (i < NN) offsets[i] = ex;
    if (threadIdx.x == 0) bsum[blockIdx.x] = total;
}

__global__ __launch_bounds__(256)
void scan_bsum_kernel(int* __restrict__ bsum)
{
    __shared__ int lds4[4];
    int t = threadIdx.x;
    int v = (t < SB) ? bsum[t] : 0;
    int total;
    int ex = block_excl_scan(v, lds4, &total);
    if (t < SB) bsum[t] = ex;
}

// one random 4B write per edge (src 16b | type 16b packed; N<65536, R<256)
// global position = local offsets[d] + bsum[d>>8] (scan_add folded in here)
__global__ __launch_bounds__(256)
void scatter_kernel(const int* __restrict__ ei, const int* __restrict__ et,
                    const int* __restrict__ offsets, const int* __restrict__ bsum,
                    int* __restrict__ fill, u32* __restrict__ dstorder)
{
    int e = blockIdx.x * 256 + threadIdx.x;
    if (e >= EE) return;
    int d = ei[EE + e];
    int pos = offsets[d] + bsum[d >> 8] + atomicAdd(&fill[d], 1);
    dstorder[pos] = (u32)ei[e] | ((u32)et[e] << 16);
}

// ---------------- fused per-node: logits + softmax (no-shift) + aggregate + bias + act
// one wave per dst node; 4 edge-groups of 16 lanes; lane owns 8 channels (c0=(lane&15)*8)
// xl/erel fp32: no unpack VALU in the hot loop. [R9: keep 4x16 shape, VGPR<=40]
__global__ __launch_bounds__(256)
void node_kernel(const u32* __restrict__ dstorder, const int* __restrict__ offsets,
                 const int* __restrict__ bsum,
                 const float* __restrict__ xl, const u16* __restrict__ xr,
                 const float* __restrict__ erel, const float* __restrict__ att,
                 const float* __restrict__ bias,
                 u16* __restrict__ xnext, float* __restrict__ outp, int is_last)
{
    int tid  = threadIdx.x;
    int node = blockIdx.x * 4 + (tid >> 6);
    int lane = tid & 63;
    if (node >= NN) return;
    int g  = lane >> 4;          // edge slot within quad
    int gl = lane & 15;          // channel set
    int c0 = gl * 8;
    int beg = offsets[node] + bsum[node >> 8];
    int end = (node == NN - 1) ? EE : offsets[node + 1] + bsum[(node + 1) >> 8];

    // per-node constants: xr channels (bf16, unpacked once) + att channels
    float xrf[8], attf[8];
    {
        const u32* xp = (const u32*)&xr[(size_t)node * DD + c0];
        #pragma unroll
        for (int q = 0; q < 4; q++) bf2x(xp[q], xrf[q*2], xrf[q*2+1]);
        float4 a0 = *(const float4*)&att[c0];
        float4 a1 = *(const float4*)&att[c0 + 4];
        attf[0]=a0.x; attf[1]=a0.y; attf[2]=a0.z; attf[3]=a0.w;
        attf[4]=a1.x; attf[5]=a1.y; attf[6]=a1.z; attf[7]=a1.w;
    }

    float s = 0.f;
    float a[8];
    #pragma unroll
    for (int j = 0; j < 8; j++) a[j] = 0.f;

    for (int base = beg; base < end; base += 4) {
        int es = base + g;
        bool valid = es < end;
        u32 st = valid ? dstorder[es] : 0;
        int src = st & 0xffff;
        int typ = st >> 16;
        const float* xp = xl + (size_t)src * DD + c0;
        const float* ep = erel + (size_t)typ * DD + c0;
        float4 x0 = *(const float4*)xp;
        float4 x1 = *(const float4*)(xp + 4);
        float4 e0 = *(const float4*)ep;
        float4 e1 = *(const float4*)(ep + 4);
        float xf[8] = {x0.x, x0.y, x0.z, x0.w, x1.x, x1.y, x1.z, x1.w};
        float ef[8] = {e0.x, e0.y, e0.z, e0.w, e1.x, e1.y, e1.z, e1.w};
        float p = 0.f;
        #pragma unroll
        for (int j = 0; j < 8; j++) {
            float m = xf[j] + xrf[j] + ef[j];
            m = fmaxf(m, 0.2f * m);         // leaky_relu (slope<1): max(x, 0.2x)
            p += m * attf[j];
        }
        // per-head logit: reduce over the 4 lanes of this head (gl span of 4)
        p += __shfl_xor(p, 1, 64);
        p += __shfl_xor(p, 2, 64);
        // softmax without max-shift: logits are O(1); clamp guards inf
        float w = valid ? __expf(fminf(p, 60.f)) : 0.f;
        s += w;
        #pragma unroll
        for (int j = 0; j < 8; j++) a[j] += w * xf[j];
    }

    // cross-group reduction (groups processed disjoint edges)
    #pragma unroll
    for (int j = 0; j < 8; j++) {
        a[j] += __shfl_xor(a[j], 16, 64);
        a[j] += __shfl_xor(a[j], 32, 64);
    }
    s += __shfl_xor(s, 16, 64);
    s += __shfl_xor(s, 32, 64);

    if (lane < 16) {
        float rh = 1.f / fmaxf(s, 1e-30f);
        float4 b0 = *(const float4*)&bias[c0];
        float4 b1 = *(const float4*)&bias[c0 + 4];
        float bv[8] = {b0.x, b0.y, b0.z, b0.w, b1.x, b1.y, b1.z, b1.w};
        float v[8];
        #pragma unroll
        for (int j = 0; j < 8; j++) v[j] = a[j] * rh + bv[j];
        if (is_last) {
            float4* op = (float4*)&outp[(size_t)node * DD + c0];
            op[0] = make_float4(v[0], v[1], v[2], v[3]);
            op[1] = make_float4(v[4], v[5], v[6], v[7]);
        } else {
            u16 pk[8];
            #pragma unroll
            for (int j = 0; j < 8; j++) {
                float w2 = v[j] > 0.f ? v[j] : __expf(v[j]) - 1.f;   // elu
                pk[j] = f2bf(w2);
            }
            *(short8*)&xnext[(size_t)node * DD + c0] = *(short8*)pk;
        }
    }
}

extern "C" void kernel_launch(void* const* d_in, const int* in_sizes, int n_in,
                              void* d_out, int out_size, void* d_ws, size_t ws_size,
                              hipStream_t stream)
{
    const int*   entity        = (const int*)d_in[0];
    const int*   edge_index    = (const int*)d_in[1];
    const int*   edge_type     = (const int*)d_in[2];
    const float* node_features = (const float*)d_in[3];
    const float* rel_emb       = (const float*)d_in[4];
    const float* proj_w        = (const float*)d_in[5];
    const float* proj_b        = (const float*)d_in[6];
    const float* w_l           = (const float*)d_in[7];
    const float* b_l           = (const float*)d_in[8];
    const float* w_r           = (const float*)d_in[9];
    const float* b_r           = (const float*)d_in[10];
    const float* w_e           = (const float*)d_in[11];
    const float* att           = (const float*)d_in[12];
    const float* bias          = (const float*)d_in[13];

    // workspace (~56 MB):
    u16*   xb      = (u16*)d_ws;                           // NN*DD bf16 (layer input)
    float* xlf     = (float*)(xb + (size_t)NN * DD);       // NN*DD fp32 (node gather)
    u16*   xr      = (u16*)(xlf + (size_t)NN * DD);        // NN*DD bf16
    float* erel    = (float*)(xr + (size_t)NN * DD);       // LL*RR*DD fp32
    u16*   wt      = (u16*)(erel + (size_t)LL * RR * DD);  // WTOT bf16
    u32*   dstorder= (u32*)(wt + WTOT);                    // EE u32 (src|type, dst-order)
    int*   counts  = (int*)(dstorder + (size_t)EE);        // NN int
    int*   fill    = counts + NN;                          // NN int
    int*   offsets = fill + NN;                            // NN int (local scans)
    int*   bsum    = offsets + NN;                         // SB int

    // ---- prep: zero counts+fill, then fused hist | wconv | relproj
    hipMemsetAsync(counts, 0, (size_t)NN * 2 * sizeof(int), stream);
    prep_kernel<<<HB + WB + RB, 256, 0, stream>>>(
        edge_index, counts, proj_w, w_l, w_r, wt, rel_emb, w_e, erel);

    // ---- CSR: two-level scan + packed scatter (edges constant across layers)
    scan_local_kernel<<<SB, 256, 0, stream>>>(counts, offsets, bsum);
    scan_bsum_kernel<<<1, 256, 0, stream>>>(bsum);
    scatter_kernel<<<(EE + 255) / 256, 256, 0, stream>>>(
        edge_index, edge_type, offsets, bsum, fill, dstorder);

    const u16* wtProj = wt;
    const int GB = (NN + 127) / 128;
    gemm_mfma_kernel<false, true, false><<<dim3(GB, 1), 256, 0, stream>>>(
        node_features, entity, FF, PK, FF, PK,
        wtProj, proj_b, xb, wtProj, proj_b, xb, NN);

    for (int l = 0; l < LL; l++) {
        const u16* wtl = wt + 128 * PK + l * 16384;
        const u16* wtr = wt + 128 * PK + 32768 + l * 16384;
        // y=0 -> xl fp32 out; y=1 -> xr bf16 out
        gemm_mfma_kernel<true, false, true><<<dim3(GB, 2), 256, 0, stream>>>(
            xb, nullptr, DD, DD, DD, DD,
            wtl, b_l + l * DD, xlf,
            wtr, b_r + l * DD, xr, NN);

        node_kernel<<<(NN + 3) / 4, 256, 0, stream>>>(
            dstorder, offsets, bsum, xlf, xr, erel + (size_t)l * RR * DD,
            att + (size_t)l * DD, bias + (size_t)l * DD,
            xb, (float*)d_out, l == LL - 1);
    }
}

// Round 13
// 340.914 us; speedup vs baseline: 1.1194x; 1.1194x over previous
//
#include <hip/hip_runtime.h>

#define NN 50000
#define FF 300
#define DD 128
#define HH 4
#define CC 32
#define EE 640000
#define RR 200
#define LL 2
#define SB ((NN + 255) / 256)     // scan blocks = 196
#define PK 320                    // proj K padded to multiple of 64
#define WTOT (128 * PK + 4 * 128 * 128)
#define HB ((EE + 255) / 256)     // hist blocks in prep
#define WB ((WTOT + 255) / 256)   // wconv blocks in prep
#define RB (LL * RR / 2)          // relproj blocks in prep (2 lr per block)

typedef unsigned short u16;
typedef unsigned int u32;
typedef __attribute__((ext_vector_type(8))) short short8;   // 8 bf16 (4 VGPRs)
typedef __attribute__((ext_vector_type(4))) float floatx4;  // MFMA accumulator

__device__ __forceinline__ float bf2f(u16 u) {
    union { u32 i; float f; } v; v.i = ((u32)u) << 16; return v.f;
}
__device__ __forceinline__ u16 f2bf(float f) {
    u32 u = __float_as_uint(f);
    u32 r = (u >> 16) & 1u;
    u += 0x7fffu + r;
    return (u16)(u >> 16);
}
// unpack 2 bf16 from one u32 (lo = lower address = even channel)
__device__ __forceinline__ void bf2x(u32 p, float& lo, float& hi) {
    lo = __uint_as_float(p << 16);
    hi = __uint_as_float(p & 0xffff0000u);
}

// block-wide (256 threads) scan: returns exclusive prefix of v; *total = block sum
__device__ __forceinline__ int block_excl_scan(int v, int* lds4, int* total) {
    int lane = threadIdx.x & 63, wid = threadIdx.x >> 6;
    int x = v;
    #pragma unroll
    for (int off = 1; off < 64; off <<= 1) {
        int y = __shfl_up(x, off, 64);
        if (lane >= off) x += y;
    }
    if (lane == 63) lds4[wid] = x;
    __syncthreads();
    int add = 0;
    #pragma unroll
    for (int w = 0; w < 4; w++) add += (w < wid) ? lds4[w] : 0;
    *total = lds4[0] + lds4[1] + lds4[2] + lds4[3];
    return x + add - v;
}

// ---------------- fused prep: hist | weight transpose-convert | relproj (fp32 out)
__global__ __launch_bounds__(256)
void prep_kernel(const int* __restrict__ ei, int* __restrict__ counts,
                 const float* __restrict__ proj_w, const float* __restrict__ w_l,
                 const float* __restrict__ w_r, u16* __restrict__ wt,
                 const float* __restrict__ rel_emb, const float* __restrict__ w_e,
                 float* __restrict__ erel)
{
    __shared__ float rv[2][DD];
    int b = blockIdx.x, tid = threadIdx.x;
    if (b < HB) {
        // degree histogram
        int e = b * 256 + tid;
        if (e < EE) atomicAdd(&counts[ei[EE + e]], 1);
    } else if (b < HB + WB) {
        // fp32 [K][128] -> bf16 WT [128][K]: [proj 128xPK pad0] [wl0][wl1][wr0][wr1]
        int i = (b - HB) * 256 + tid;
        if (i < WTOT) {
            float v;
            if (i < 128 * PK) {
                int n = i / PK, k = i - n * PK;
                v = (k < FF) ? proj_w[(size_t)k * DD + n] : 0.f;
            } else {
                int j = i - 128 * PK;
                int seg = j >> 14;          // wl0, wl1, wr0, wr1
                int r = j & 16383;
                int n = r >> 7, k = r & 127;
                const float* src = (seg < 2) ? (w_l + (size_t)seg * DD * DD)
                                             : (w_r + (size_t)(seg - 2) * DD * DD);
                v = src[(size_t)k * DD + n];
            }
            wt[i] = f2bf(v);
        }
    } else {
        // erel[l*RR+r][d] = rel_emb[r,:] @ w_e[l][:,d]   (2 lr per block, fp32 out)
        int half = tid >> 7, d = tid & 127;
        int lr = (b - HB - WB) * 2 + half;
        int l = lr / RR, r = lr - l * RR;
        rv[half][d] = rel_emb[r * DD + d];
        __syncthreads();
        const float* W = w_e + (size_t)l * DD * DD;
        float acc = 0.f;
        #pragma unroll 8
        for (int k = 0; k < DD; k++) acc += rv[half][k] * W[k * DD + d];
        erel[(size_t)lr * DD + d] = acc;
    }
}

// ---------------- MFMA bf16 GEMM, BK=64: C[M,128] = A[M,Ka] @ WT^T + bias, out bf16
// [R12 post-mortem: fp32 xl output doubled the node gather stream, node 46->57us.
//  Both outputs stay bf16.]
template<bool ABF16, bool GATHER>
__global__ __launch_bounds__(256)
void gemm_mfma_kernel(const void* __restrict__ A_, const int* __restrict__ rowidx,
                      int lda, int K, int Ka, int ldb,
                      const u16* __restrict__ BT1, const float* __restrict__ bias1,
                      u16* __restrict__ C1,
                      const u16* __restrict__ BT2, const float* __restrict__ bias2,
                      u16* __restrict__ C2, int M)
{
    const u16*   BT   = (blockIdx.y == 0) ? BT1 : BT2;
    const float* bias = (blockIdx.y == 0) ? bias1 : bias2;
    u16*         Cout = (blockIdx.y == 0) ? C1 : C2;

    // pad 8 u16 -> 144 B rows: bank stride 4, 2-way conflicts only (free, m136)
    __shared__ u16 As[128][72];
    __shared__ u16 Bs[128][72];   // Bs[n][k]
    int tid  = threadIdx.x;
    int m0   = blockIdx.x * 128;
    int wave = tid >> 6, lane = tid & 63;
    int quad = lane >> 4, l16 = lane & 15;
    int wrow = (wave >> 1) * 64, wcol = (wave & 1) * 64;

    floatx4 acc[4][4];
    #pragma unroll
    for (int i = 0; i < 4; i++)
        #pragma unroll
        for (int j = 0; j < 4; j++) acc[i][j] = (floatx4){0.f, 0.f, 0.f, 0.f};

    int ar = tid >> 1, ah = tid & 1;   // row, k-half (32 each)
    int arow = m0 + ar;
    int rid = (arow < M) ? (GATHER ? rowidx[arow] : arow) : 0;

    for (int kk = 0; kk < K; kk += 64) {
        #pragma unroll
        for (int q = 0; q < 2; q++) {
            int kb = kk + ah * 32 + q * 16;
            u16 tmp[16];
            if (ABF16) {
                const u16* Ap = (const u16*)A_ + (size_t)rid * lda + kb;
                if (kb + 16 <= Ka) {
                    *(short8*)&tmp[0] = *(const short8*)Ap;
                    *(short8*)&tmp[8] = *(const short8*)(Ap + 8);
                } else {
                    #pragma unroll
                    for (int j = 0; j < 16; j++) tmp[j] = (kb + j < Ka) ? Ap[j] : (u16)0;
                }
            } else {
                const float* Ap = (const float*)A_ + (size_t)rid * lda + kb;
                if (kb + 16 <= Ka) {
                    #pragma unroll
                    for (int qq = 0; qq < 4; qq++) {
                        float4 f = *(const float4*)(Ap + qq * 4);
                        tmp[qq*4+0] = f2bf(f.x); tmp[qq*4+1] = f2bf(f.y);
                        tmp[qq*4+2] = f2bf(f.z); tmp[qq*4+3] = f2bf(f.w);
                    }
                } else {
                    #pragma unroll
                    for (int j = 0; j < 16; j++) tmp[j] = (kb + j < Ka) ? f2bf(Ap[j]) : (u16)0;
                }
            }
            *(short8*)&As[ar][ah * 32 + q * 16]     = *(short8*)&tmp[0];
            *(short8*)&As[ar][ah * 32 + q * 16 + 8] = *(short8*)&tmp[8];
        }
        {
            const u16* Bp = BT + (size_t)ar * ldb + kk + ah * 32;
            #pragma unroll
            for (int q = 0; q < 4; q++)
                *(short8*)&Bs[ar][ah * 32 + q * 8] = *(const short8*)(Bp + q * 8);
        }
        __syncthreads();
        #pragma unroll
        for (int ks = 0; ks < 2; ks++) {
            short8 af[4], bfr[4];
            #pragma unroll
            for (int i = 0; i < 4; i++)
                af[i] = *(const short8*)&As[wrow + i * 16 + l16][ks * 32 + quad * 8];
            #pragma unroll
            for (int j = 0; j < 4; j++)
                bfr[j] = *(const short8*)&Bs[wcol + j * 16 + l16][ks * 32 + quad * 8];
            #pragma unroll
            for (int i = 0; i < 4; i++)
                #pragma unroll
                for (int j = 0; j < 4; j++)
                    acc[i][j] = __builtin_amdgcn_mfma_f32_16x16x32_bf16(
                        af[i], bfr[j], acc[i][j], 0, 0, 0);
        }
        __syncthreads();
    }

    // epilogue: C/D layout col=lane&15, row=quad*4+reg (m89)
    #pragma unroll
    for (int i = 0; i < 4; i++) {
        #pragma unroll
        for (int rr = 0; rr < 4; rr++) {
            int row = m0 + wrow + i * 16 + quad * 4 + rr;
            if (row < M) {
                #pragma unroll
                for (int j = 0; j < 4; j++) {
                    int col = wcol + j * 16 + l16;
                    Cout[(size_t)row * DD + col] = f2bf(acc[i][j][rr] + bias[col]);
                }
            }
        }
    }
}

// ---------------- CSR scan (two-level, add folded into consumers) + scatter
__global__ __launch_bounds__(256)
void scan_local_kernel(const int* __restrict__ counts, int* __restrict__ offsets,
                       int* __restrict__ bsum)
{
    __shared__ int lds4[4];
    int i = blockIdx.x * 256 + threadIdx.x;
    int v = (i < NN) ? counts[i] : 0;
    int total;
    int ex = block_excl_scan(v, lds4, &total);
    if (i < NN) offsets[i] = ex;
    if (threadIdx.x == 0) bsum[blockIdx.x] = total;
}

__global__ __launch_bounds__(256)
void scan_bsum_kernel(int* __restrict__ bsum)
{
    __shared__ int lds4[4];
    int t = threadIdx.x;
    int v = (t < SB) ? bsum[t] : 0;
    int total;
    int ex = block_excl_scan(v, lds4, &total);
    if (t < SB) bsum[t] = ex;
}

// one random 4B write per edge (src 16b | type 16b packed; N<65536, R<256)
__global__ __launch_bounds__(256)
void scatter_kernel(const int* __restrict__ ei, const int* __restrict__ et,
                    const int* __restrict__ offsets, const int* __restrict__ bsum,
                    int* __restrict__ fill, u32* __restrict__ dstorder)
{
    int e = blockIdx.x * 256 + threadIdx.x;
    if (e >= EE) return;
    int d = ei[EE + e];
    int pos = offsets[d] + bsum[d >> 8] + atomicAdd(&fill[d], 1);
    dstorder[pos] = (u32)ei[e] | ((u32)et[e] << 16);
}

// ---------------- fused per-node: logits + softmax (no-shift) + aggregate + bias + act
// one wave per dst node; 4 edge-groups of 16 lanes; lane owns 8 channels (c0=(lane&15)*8)
// xl bf16 (gather-cheap, R12 fp32 regressed); erel fp32 (L2-hot, no unpack VALU).
__global__ __launch_bounds__(256)
void node_kernel(const u32* __restrict__ dstorder, const int* __restrict__ offsets,
                 const int* __restrict__ bsum,
                 const u16* __restrict__ xl, const u16* __restrict__ xr,
                 const float* __restrict__ erel, const float* __restrict__ att,
                 const float* __restrict__ bias,
                 u16* __restrict__ xnext, float* __restrict__ outp, int is_last)
{
    int tid  = threadIdx.x;
    int node = blockIdx.x * 4 + (tid >> 6);
    int lane = tid & 63;
    if (node >= NN) return;
    int g  = lane >> 4;          // edge slot within quad
    int gl = lane & 15;          // channel set
    int c0 = gl * 8;
    int beg = offsets[node] + bsum[node >> 8];
    int end = (node == NN - 1) ? EE : offsets[node + 1] + bsum[(node + 1) >> 8];

    // per-node constants: xr channels (bf16, unpacked once) + att channels
    float xrf[8], attf[8];
    {
        const u32* xp = (const u32*)&xr[(size_t)node * DD + c0];
        #pragma unroll
        for (int q = 0; q < 4; q++) bf2x(xp[q], xrf[q*2], xrf[q*2+1]);
        float4 a0 = *(const float4*)&att[c0];
        float4 a1 = *(const float4*)&att[c0 + 4];
        attf[0]=a0.x; attf[1]=a0.y; attf[2]=a0.z; attf[3]=a0.w;
        attf[4]=a1.x; attf[5]=a1.y; attf[6]=a1.z; attf[7]=a1.w;
    }

    float s = 0.f;
    float a[8];
    #pragma unroll
    for (int j = 0; j < 8; j++) a[j] = 0.f;

    for (int base = beg; base < end; base += 4) {
        int es = base + g;
        bool valid = es < end;
        u32 st = valid ? dstorder[es] : 0;
        int src = st & 0xffff;
        int typ = st >> 16;
        const u32*   xp = (const u32*)&xl[(size_t)src * DD + c0];
        const float* ep = erel + (size_t)typ * DD + c0;
        u32 xv0 = xp[0], xv1 = xp[1], xv2 = xp[2], xv3 = xp[3];
        float4 e0 = *(const float4*)ep;
        float4 e1 = *(const float4*)(ep + 4);
        float xf[8];
        bf2x(xv0, xf[0], xf[1]); bf2x(xv1, xf[2], xf[3]);
        bf2x(xv2, xf[4], xf[5]); bf2x(xv3, xf[6], xf[7]);
        float ef[8] = {e0.x, e0.y, e0.z, e0.w, e1.x, e1.y, e1.z, e1.w};
        float p = 0.f;
        #pragma unroll
        for (int j = 0; j < 8; j++) {
            float m = xf[j] + xrf[j] + ef[j];
            m = fmaxf(m, 0.2f * m);         // leaky_relu (slope<1): max(x, 0.2x)
            p += m * attf[j];
        }
        // per-head logit: reduce over the 4 lanes of this head (gl span of 4)
        p += __shfl_xor(p, 1, 64);
        p += __shfl_xor(p, 2, 64);
        // softmax without max-shift: logits are O(1); clamp guards inf
        float w = valid ? __expf(fminf(p, 60.f)) : 0.f;
        s += w;
        #pragma unroll
        for (int j = 0; j < 8; j++) a[j] += w * xf[j];
    }

    // cross-group reduction (groups processed disjoint edges)
    #pragma unroll
    for (int j = 0; j < 8; j++) {
        a[j] += __shfl_xor(a[j], 16, 64);
        a[j] += __shfl_xor(a[j], 32, 64);
    }
    s += __shfl_xor(s, 16, 64);
    s += __shfl_xor(s, 32, 64);

    if (lane < 16) {
        float rh = 1.f / fmaxf(s, 1e-30f);
        float4 b0 = *(const float4*)&bias[c0];
        float4 b1 = *(const float4*)&bias[c0 + 4];
        float bv[8] = {b0.x, b0.y, b0.z, b0.w, b1.x, b1.y, b1.z, b1.w};
        float v[8];
        #pragma unroll
        for (int j = 0; j < 8; j++) v[j] = a[j] * rh + bv[j];
        if (is_last) {
            float4* op = (float4*)&outp[(size_t)node * DD + c0];
            op[0] = make_float4(v[0], v[1], v[2], v[3]);
            op[1] = make_float4(v[4], v[5], v[6], v[7]);
        } else {
            u16 pk[8];
            #pragma unroll
            for (int j = 0; j < 8; j++) {
                float w2 = v[j] > 0.f ? v[j] : __expf(v[j]) - 1.f;   // elu
                pk[j] = f2bf(w2);
            }
            *(short8*)&xnext[(size_t)node * DD + c0] = *(short8*)pk;
        }
    }
}

extern "C" void kernel_launch(void* const* d_in, const int* in_sizes, int n_in,
                              void* d_out, int out_size, void* d_ws, size_t ws_size,
                              hipStream_t stream)
{
    const int*   entity        = (const int*)d_in[0];
    const int*   edge_index    = (const int*)d_in[1];
    const int*   edge_type     = (const int*)d_in[2];
    const float* node_features = (const float*)d_in[3];
    const float* rel_emb       = (const float*)d_in[4];
    const float* proj_w        = (const float*)d_in[5];
    const float* proj_b        = (const float*)d_in[6];
    const float* w_l           = (const float*)d_in[7];
    const float* b_l           = (const float*)d_in[8];
    const float* w_r           = (const float*)d_in[9];
    const float* b_r           = (const float*)d_in[10];
    const float* w_e           = (const float*)d_in[11];
    const float* att           = (const float*)d_in[12];
    const float* bias          = (const float*)d_in[13];

    // workspace (~33 MB):
    u16*   xb      = (u16*)d_ws;                           // NN*DD bf16 (layer input)
    u16*   xl      = xb + (size_t)NN * DD;                 // NN*DD bf16
    u16*   xr      = xl + (size_t)NN * DD;                 // NN*DD bf16
    float* erel    = (float*)(xr + (size_t)NN * DD);       // LL*RR*DD fp32
    u16*   wt      = (u16*)(erel + (size_t)LL * RR * DD);  // WTOT bf16
    u32*   dstorder= (u32*)(wt + WTOT);                    // EE u32 (src|type, dst-order)
    int*   counts  = (int*)(dstorder + (size_t)EE);        // NN int
    int*   fill    = counts + NN;                          // NN int
    int*   offsets = fill + NN;                            // NN int (local scans)
    int*   bsum    = offsets + NN;                         // SB int

    // ---- prep: zero counts+fill, then fused hist | wconv | relproj
    hipMemsetAsync(counts, 0, (size_t)NN * 2 * sizeof(int), stream);
    prep_kernel<<<HB + WB + RB, 256, 0, stream>>>(
        edge_index, counts, proj_w, w_l, w_r, wt, rel_emb, w_e, erel);

    // ---- CSR: two-level scan + packed scatter (edges constant across layers)
    scan_local_kernel<<<SB, 256, 0, stream>>>(counts, offsets, bsum);
    scan_bsum_kernel<<<1, 256, 0, stream>>>(bsum);
    scatter_kernel<<<(EE + 255) / 256, 256, 0, stream>>>(
        edge_index, edge_type, offsets, bsum, fill, dstorder);

    const u16* wtProj = wt;
    const int GB = (NN + 127) / 128;
    gemm_mfma_kernel<false, true><<<dim3(GB, 1), 256, 0, stream>>>(
        node_features, entity, FF, PK, FF, PK,
        wtProj, proj_b, xb, wtProj, proj_b, xb, NN);

    for (int l = 0; l < LL; l++) {
        const u16* wtl = wt + 128 * PK + l * 16384;
        const u16* wtr = wt + 128 * PK + 32768 + l * 16384;
        gemm_mfma_kernel<true, false><<<dim3(GB, 2), 256, 0, stream>>>(
            xb, nullptr, DD, DD, DD, DD,
            wtl, b_l + l * DD, xl,
            wtr, b_r + l * DD, xr, NN);

        node_kernel<<<(NN + 3) / 4, 256, 0, stream>>>(
            dstorder, offsets, bsum, xl, xr, erel + (size_t)l * RR * DD,
            att + (size_t)l * DD, bias + (size_t)l * DD,
            xb, (float*)d_out, l == LL - 1);
    }
}

// Round 14
// 334.832 us; speedup vs baseline: 1.1397x; 1.0182x over previous
//
#include <hip/hip_runtime.h>

#define NN 50000
#define FF 300
#define DD 128
#define HH 4
#define CC 32
#define EE 640000
#define RR 200
#define LL 2
#define SB ((NN + 255) / 256)     // scan blocks = 196
#define PK 320                    // proj K padded to multiple of 64
#define WTOT (128 * PK + 4 * 128 * 128)
#define HB ((EE + 255) / 256)     // hist blocks in prep
#define WB ((WTOT + 255) / 256)   // wconv blocks in prep
#define RB (LL * RR / 2)          // relproj blocks in prep (2 lr per block)

typedef unsigned short u16;
typedef unsigned int u32;
typedef _Float16 h2   __attribute__((ext_vector_type(2)));
typedef _Float16 half8 __attribute__((ext_vector_type(8)));  // MFMA A/B frag (4 VGPRs)
typedef __attribute__((ext_vector_type(4))) float floatx4;   // MFMA accumulator

__device__ __forceinline__ u16 f2h(float f) {
    union { _Float16 h; u16 u; } v; v.h = (_Float16)f; return v.u;
}
__device__ __forceinline__ float h2f(u16 u) {
    union { u16 u; _Float16 h; } v; v.u = u; return (float)v.h;
}
__device__ __forceinline__ h2 u2h2(u32 p) {
    union { u32 u; h2 h; } v; v.u = p; return v.h;
}
__device__ __forceinline__ h2 hmax2(h2 a, h2 b) {
#if __has_builtin(__builtin_elementwise_max)
    return __builtin_elementwise_max(a, b);
#else
    h2 r; r.x = a.x > b.x ? a.x : b.x; r.y = a.y > b.y ? a.y : b.y; return r;
#endif
}
__device__ __forceinline__ float hdot2(h2 a, h2 b, float c) {
#if __has_builtin(__builtin_amdgcn_fdot2)
    return __builtin_amdgcn_fdot2(a, b, c, false);
#else
    return c + (float)a.x * (float)b.x + (float)a.y * (float)b.y;
#endif
}

// block-wide (256 threads) scan: returns exclusive prefix of v; *total = block sum
__device__ __forceinline__ int block_excl_scan(int v, int* lds4, int* total) {
    int lane = threadIdx.x & 63, wid = threadIdx.x >> 6;
    int x = v;
    #pragma unroll
    for (int off = 1; off < 64; off <<= 1) {
        int y = __shfl_up(x, off, 64);
        if (lane >= off) x += y;
    }
    if (lane == 63) lds4[wid] = x;
    __syncthreads();
    int add = 0;
    #pragma unroll
    for (int w = 0; w < 4; w++) add += (w < wid) ? lds4[w] : 0;
    *total = lds4[0] + lds4[1] + lds4[2] + lds4[3];
    return x + add - v;
}

// ---------------- fused prep: hist | weight transpose-convert | relproj (all fp16 out)
__global__ __launch_bounds__(256)
void prep_kernel(const int* __restrict__ ei, int* __restrict__ counts,
                 const float* __restrict__ proj_w, const float* __restrict__ w_l,
                 const float* __restrict__ w_r, u16* __restrict__ wt,
                 const float* __restrict__ rel_emb, const float* __restrict__ w_e,
                 u16* __restrict__ erel)
{
    __shared__ float rv[2][DD];
    int b = blockIdx.x, tid = threadIdx.x;
    if (b < HB) {
        // degree histogram
        int e = b * 256 + tid;
        if (e < EE) atomicAdd(&counts[ei[EE + e]], 1);
    } else if (b < HB + WB) {
        // fp32 [K][128] -> fp16 WT [128][K]: [proj 128xPK pad0] [wl0][wl1][wr0][wr1]
        int i = (b - HB) * 256 + tid;
        if (i < WTOT) {
            float v;
            if (i < 128 * PK) {
                int n = i / PK, k = i - n * PK;
                v = (k < FF) ? proj_w[(size_t)k * DD + n] : 0.f;
            } else {
                int j = i - 128 * PK;
                int seg = j >> 14;          // wl0, wl1, wr0, wr1
                int r = j & 16383;
                int n = r >> 7, k = r & 127;
                const float* src = (seg < 2) ? (w_l + (size_t)seg * DD * DD)
                                             : (w_r + (size_t)(seg - 2) * DD * DD);
                v = src[(size_t)k * DD + n];
            }
            wt[i] = f2h(v);
        }
    } else {
        // erel[l*RR+r][d] = rel_emb[r,:] @ w_e[l][:,d]   (2 lr per block, fp16 out)
        int half = tid >> 7, d = tid & 127;
        int lr = (b - HB - WB) * 2 + half;
        int l = lr / RR, r = lr - l * RR;
        rv[half][d] = rel_emb[r * DD + d];
        __syncthreads();
        const float* W = w_e + (size_t)l * DD * DD;
        float acc = 0.f;
        #pragma unroll 8
        for (int k = 0; k < DD; k++) acc += rv[half][k] * W[k * DD + d];
        erel[(size_t)lr * DD + d] = f2h(acc);
    }
}

// ---------------- MFMA fp16 GEMM, BK=64: C[M,128] = A[M,Ka] @ WT^T + bias, out fp16
template<bool AF16, bool GATHER>
__global__ __launch_bounds__(256)
void gemm_mfma_kernel(const void* __restrict__ A_, const int* __restrict__ rowidx,
                      int lda, int K, int Ka, int ldb,
                      const u16* __restrict__ BT1, const float* __restrict__ bias1,
                      u16* __restrict__ C1,
                      const u16* __restrict__ BT2, const float* __restrict__ bias2,
                      u16* __restrict__ C2, int M)
{
    const u16*   BT   = (blockIdx.y == 0) ? BT1 : BT2;
    const float* bias = (blockIdx.y == 0) ? bias1 : bias2;
    u16*         Cout = (blockIdx.y == 0) ? C1 : C2;

    // pad 8 u16 -> 144 B rows: bank stride 4, 2-way conflicts only (free, m136)
    __shared__ u16 As[128][72];
    __shared__ u16 Bs[128][72];   // Bs[n][k]
    int tid  = threadIdx.x;
    int m0   = blockIdx.x * 128;
    int wave = tid >> 6, lane = tid & 63;
    int quad = lane >> 4, l16 = lane & 15;
    int wrow = (wave >> 1) * 64, wcol = (wave & 1) * 64;

    floatx4 acc[4][4];
    #pragma unroll
    for (int i = 0; i < 4; i++)
        #pragma unroll
        for (int j = 0; j < 4; j++) acc[i][j] = (floatx4){0.f, 0.f, 0.f, 0.f};

    int ar = tid >> 1, ah = tid & 1;   // row, k-half (32 each)
    int arow = m0 + ar;
    int rid = (arow < M) ? (GATHER ? rowidx[arow] : arow) : 0;

    for (int kk = 0; kk < K; kk += 64) {
        #pragma unroll
        for (int q = 0; q < 2; q++) {
            int kb = kk + ah * 32 + q * 16;
            u16 tmp[16];
            if (AF16) {
                const u16* Ap = (const u16*)A_ + (size_t)rid * lda + kb;
                if (kb + 16 <= Ka) {
                    *(half8*)&tmp[0] = *(const half8*)Ap;
                    *(half8*)&tmp[8] = *(const half8*)(Ap + 8);
                } else {
                    #pragma unroll
                    for (int j = 0; j < 16; j++) tmp[j] = (kb + j < Ka) ? Ap[j] : (u16)0;
                }
            } else {
                const float* Ap = (const float*)A_ + (size_t)rid * lda + kb;
                if (kb + 16 <= Ka) {
                    #pragma unroll
                    for (int qq = 0; qq < 4; qq++) {
                        float4 f = *(const float4*)(Ap + qq * 4);
                        tmp[qq*4+0] = f2h(f.x); tmp[qq*4+1] = f2h(f.y);
                        tmp[qq*4+2] = f2h(f.z); tmp[qq*4+3] = f2h(f.w);
                    }
                } else {
                    #pragma unroll
                    for (int j = 0; j < 16; j++) tmp[j] = (kb + j < Ka) ? f2h(Ap[j]) : (u16)0;
                }
            }
            *(half8*)&As[ar][ah * 32 + q * 16]     = *(half8*)&tmp[0];
            *(half8*)&As[ar][ah * 32 + q * 16 + 8] = *(half8*)&tmp[8];
        }
        {
            const u16* Bp = BT + (size_t)ar * ldb + kk + ah * 32;
            #pragma unroll
            for (int q = 0; q < 4; q++)
                *(half8*)&Bs[ar][ah * 32 + q * 8] = *(const half8*)(Bp + q * 8);
        }
        __syncthreads();
        #pragma unroll
        for (int ks = 0; ks < 2; ks++) {
            half8 af[4], bfr[4];
            #pragma unroll
            for (int i = 0; i < 4; i++)
                af[i] = *(const half8*)&As[wrow + i * 16 + l16][ks * 32 + quad * 8];
            #pragma unroll
            for (int j = 0; j < 4; j++)
                bfr[j] = *(const half8*)&Bs[wcol + j * 16 + l16][ks * 32 + quad * 8];
            #pragma unroll
            for (int i = 0; i < 4; i++)
                #pragma unroll
                for (int j = 0; j < 4; j++)
                    acc[i][j] = __builtin_amdgcn_mfma_f32_16x16x32_f16(
                        af[i], bfr[j], acc[i][j], 0, 0, 0);
        }
        __syncthreads();
    }

    // epilogue: C/D layout col=lane&15, row=quad*4+reg (m89; dtype-independent m121)
    #pragma unroll
    for (int i = 0; i < 4; i++) {
        #pragma unroll
        for (int rr = 0; rr < 4; rr++) {
            int row = m0 + wrow + i * 16 + quad * 4 + rr;
            if (row < M) {
                #pragma unroll
                for (int j = 0; j < 4; j++) {
                    int col = wcol + j * 16 + l16;
                    Cout[(size_t)row * DD + col] = f2h(acc[i][j][rr] + bias[col]);
                }
            }
        }
    }
}

// ---------------- CSR scan (two-level, add folded into consumers) + scatter
__global__ __launch_bounds__(256)
void scan_local_kernel(const int* __restrict__ counts, int* __restrict__ offsets,
                       int* __restrict__ bsum)
{
    __shared__ int lds4[4];
    int i = blockIdx.x * 256 + threadIdx.x;
    int v = (i < NN) ? counts[i] : 0;
    int total;
    int ex = block_excl_scan(v, lds4, &total);
    if (i < NN) offsets[i] = ex;
    if (threadIdx.x == 0) bsum[blockIdx.x] = total;
}

__global__ __launch_bounds__(256)
void scan_bsum_kernel(int* __restrict__ bsum)
{
    __shared__ int lds4[4];
    int t = threadIdx.x;
    int v = (t < SB) ? bsum[t] : 0;
    int total;
    int ex = block_excl_scan(v, lds4, &total);
    if (t < SB) bsum[t] = ex;
}

// one random 4B write per edge (src 16b | type 16b packed; N<65536, R<256)
__global__ __launch_bounds__(256)
void scatter_kernel(const int* __restrict__ ei, const int* __restrict__ et,
                    const int* __restrict__ offsets, const int* __restrict__ bsum,
                    int* __restrict__ fill, u32* __restrict__ dstorder)
{
    int e = blockIdx.x * 256 + threadIdx.x;
    if (e >= EE) return;
    int d = ei[EE + e];
    int pos = offsets[d] + bsum[d >> 8] + atomicAdd(&fill[d], 1);
    dstorder[pos] = (u32)ei[e] | ((u32)et[e] << 16);
}

// ---------------- fused per-node: logits + softmax (no-shift) + aggregate + bias + act
// one wave per dst node; 4 edge-groups of 16 lanes; lane owns 8 channels (c0=(lane&15)*8)
// ALL fp16-packed math in the hot loop: pk_add/pk_max/fdot2/pk_fma, zero unpacks.
__global__ __launch_bounds__(256)
void node_kernel(const u32* __restrict__ dstorder, const int* __restrict__ offsets,
                 const int* __restrict__ bsum,
                 const u16* __restrict__ xl, const u16* __restrict__ xr,
                 const u16* __restrict__ erel, const float* __restrict__ att,
                 const float* __restrict__ bias,
                 u16* __restrict__ xnext, float* __restrict__ outp, int is_last)
{
    int tid  = threadIdx.x;
    int node = blockIdx.x * 4 + (tid >> 6);
    int lane = tid & 63;
    if (node >= NN) return;
    int g  = lane >> 4;          // edge slot within quad
    int gl = lane & 15;          // channel set
    int c0 = gl * 8;
    int beg = offsets[node] + bsum[node >> 8];
    int end = (node == NN - 1) ? EE : offsets[node + 1] + bsum[(node + 1) >> 8];

    // per-node constants (packed fp16)
    h2 xrh[4], atth[4];
    {
        const u32* xp = (const u32*)&xr[(size_t)node * DD + c0];
        #pragma unroll
        for (int q = 0; q < 4; q++) xrh[q] = u2h2(xp[q]);
        #pragma unroll
        for (int q = 0; q < 4; q++) {
            float2 av = *(const float2*)&att[c0 + q * 2];
            atth[q] = (h2){(_Float16)av.x, (_Float16)av.y};
        }
    }
    const h2 c02 = (h2){(_Float16)0.2f, (_Float16)0.2f};

    float s = 0.f;
    h2 a2[4];
    #pragma unroll
    for (int q = 0; q < 4; q++) a2[q] = (h2){(_Float16)0.f, (_Float16)0.f};

    for (int base = beg; base < end; base += 4) {
        int es = base + g;
        bool valid = es < end;
        u32 st = valid ? dstorder[es] : 0;
        int src = st & 0xffff;
        int typ = st >> 16;
        const u32* xp = (const u32*)&xl[(size_t)src * DD + c0];
        const u32* ep = (const u32*)&erel[(size_t)typ * DD + c0];
        h2 xh[4];
        float p = 0.f;
        #pragma unroll
        for (int q = 0; q < 4; q++) {
            xh[q] = u2h2(xp[q]);
            h2 m = (xh[q] + xrh[q]) + u2h2(ep[q]);   // v_pk_add_f16 x2
            m = hmax2(m, m * c02);                   // leaky: pk_mul + pk_max
            p = hdot2(m, atth[q], p);                // v_dot2_f32_f16 (fp32 acc)
        }
        // per-head logit: reduce over the 4 lanes of this head (gl span of 4)
        p += __shfl_xor(p, 1, 64);
        p += __shfl_xor(p, 2, 64);
        // softmax without max-shift: logits are O(1); clamp guards inf
        float w = valid ? __expf(fminf(p, 60.f)) : 0.f;
        s += w;
        h2 wh = (h2){(_Float16)w, (_Float16)w};
        #pragma unroll
        for (int q = 0; q < 4; q++) a2[q] += wh * xh[q];   // v_pk_fma_f16
    }

    // cross-group reduction (groups processed disjoint edges) — fp32 for safety
    float a[8];
    #pragma unroll
    for (int q = 0; q < 4; q++) { a[q*2] = (float)a2[q].x; a[q*2+1] = (float)a2[q].y; }
    #pragma unroll
    for (int j = 0; j < 8; j++) {
        a[j] += __shfl_xor(a[j], 16, 64);
        a[j] += __shfl_xor(a[j], 32, 64);
    }
    s += __shfl_xor(s, 16, 64);
    s += __shfl_xor(s, 32, 64);

    if (lane < 16) {
        float rh = 1.f / fmaxf(s, 1e-30f);
        float4 b0 = *(const float4*)&bias[c0];
        float4 b1 = *(const float4*)&bias[c0 + 4];
        float bv[8] = {b0.x, b0.y, b0.z, b0.w, b1.x, b1.y, b1.z, b1.w};
        float v[8];
        #pragma unroll
        for (int j = 0; j < 8; j++) v[j] = a[j] * rh + bv[j];
        if (is_last) {
            float4* op = (float4*)&outp[(size_t)node * DD + c0];
            op[0] = make_float4(v[0], v[1], v[2], v[3]);
            op[1] = make_float4(v[4], v[5], v[6], v[7]);
        } else {
            u16 pk[8];
            #pragma unroll
            for (int j = 0; j < 8; j++) {
                float w2 = v[j] > 0.f ? v[j] : __expf(v[j]) - 1.f;   // elu
                pk[j] = f2h(w2);
            }
            *(half8*)&xnext[(size_t)node * DD + c0] = *(half8*)pk;
        }
    }
}

extern "C" void kernel_launch(void* const* d_in, const int* in_sizes, int n_in,
                              void* d_out, int out_size, void* d_ws, size_t ws_size,
                              hipStream_t stream)
{
    const int*   entity        = (const int*)d_in[0];
    const int*   edge_index    = (const int*)d_in[1];
    const int*   edge_type     = (const int*)d_in[2];
    const float* node_features = (const float*)d_in[3];
    const float* rel_emb       = (const float*)d_in[4];
    const float* proj_w        = (const float*)d_in[5];
    const float* proj_b        = (const float*)d_in[6];
    const float* w_l           = (const float*)d_in[7];
    const float* b_l           = (const float*)d_in[8];
    const float* w_r           = (const float*)d_in[9];
    const float* b_r           = (const float*)d_in[10];
    const float* w_e           = (const float*)d_in[11];
    const float* att           = (const float*)d_in[12];
    const float* bias          = (const float*)d_in[13];

    // workspace (~33 MB), all fp16 tensors in u16 containers:
    u16*   xb      = (u16*)d_ws;                           // NN*DD (layer input)
    u16*   xl      = xb + (size_t)NN * DD;                 // NN*DD
    u16*   xr      = xl + (size_t)NN * DD;                 // NN*DD
    u16*   erel    = xr + (size_t)NN * DD;                 // LL*RR*DD
    u16*   wt      = erel + (size_t)LL * RR * DD;          // WTOT
    u32*   dstorder= (u32*)(wt + WTOT);                    // EE u32 (src|type, dst-order)
    int*   counts  = (int*)(dstorder + (size_t)EE);        // NN int
    int*   fill    = counts + NN;                          // NN int
    int*   offsets = fill + NN;                            // NN int (local scans)
    int*   bsum    = offsets + NN;                         // SB int

    // ---- prep: zero counts+fill, then fused hist | wconv | relproj
    hipMemsetAsync(counts, 0, (size_t)NN * 2 * sizeof(int), stream);
    prep_kernel<<<HB + WB + RB, 256, 0, stream>>>(
        edge_index, counts, proj_w, w_l, w_r, wt, rel_emb, w_e, erel);

    // ---- CSR: two-level scan + packed scatter (edges constant across layers)
    scan_local_kernel<<<SB, 256, 0, stream>>>(counts, offsets, bsum);
    scan_bsum_kernel<<<1, 256, 0, stream>>>(bsum);
    scatter_kernel<<<(EE + 255) / 256, 256, 0, stream>>>(
        edge_index, edge_type, offsets, bsum, fill, dstorder);

    const u16* wtProj = wt;
    const int GB = (NN + 127) / 128;
    gemm_mfma_kernel<false, true><<<dim3(GB, 1), 256, 0, stream>>>(
        node_features, entity, FF, PK, FF, PK,
        wtProj, proj_b, xb, wtProj, proj_b, xb, NN);

    for (int l = 0; l < LL; l++) {
        const u16* wtl = wt + 128 * PK + l * 16384;
        const u16* wtr = wt + 128 * PK + 32768 + l * 16384;
        gemm_mfma_kernel<true, false><<<dim3(GB, 2), 256, 0, stream>>>(
            xb, nullptr, DD, DD, DD, DD,
            wtl, b_l + l * DD, xl,
            wtr, b_r + l * DD, xr, NN);

        node_kernel<<<(NN + 3) / 4, 256, 0, stream>>>(
            dstorder, offsets, bsum, xl, xr, erel + (size_t)l * RR * DD,
            att + (size_t)l * DD, bias + (size_t)l * DD,
            xb, (float*)d_out, l == LL - 1);
    }
}